// Round 6
// baseline (639.351 us; speedup 1.0000x reference)
//
#include <hip/hip_runtime.h>
#include <hip/hip_bf16.h>
#include <cstdint>
#include <cstddef>

#define B_DIM 4
#define L_DIM 2048
#define H_DIM 1024
#define D_DIM 2048
#define N_STATE 16
#define TOKENS (B_DIM * L_DIM)   // 8192
#define CH 32                    // scan chunks
#define LC (L_DIM / CH)          // 64 steps per chunk
#define NEXT 2304                // GEMM2 padded N: 9 tiles of 256 (2048 dt + 32 B/C + pad)
#define NLIM2 2080               // real GEMM2 cols: 2048 dt + 32 BiCi

typedef __bf16 bf16x8 __attribute__((ext_vector_type(8)));
typedef float f32x4 __attribute__((ext_vector_type(4)));

__device__ __forceinline__ float sigmoidf_(float x) { return 1.f / (1.f + __expf(-x)); }
__device__ __forceinline__ float softplusf_(float x) {
  return fmaxf(x, 0.f) + log1pf(__expf(-fabsf(x)));
}
__device__ __forceinline__ void gl_lds16(const void* g, void* l) {
  __builtin_amdgcn_global_load_lds(
      (const __attribute__((address_space(1))) unsigned int*)g,
      (__attribute__((address_space(3))) unsigned int*)l, 16, 0, 0);
}

// ---------------- LayerNorm -> bf16: one block per token ----------------
__global__ __launch_bounds__(256) void ln_kernel(const float* __restrict__ x,
    const float* __restrict__ gamma, const float* __restrict__ beta,
    __hip_bfloat16* __restrict__ out) {
  int row = blockIdx.x;
  int t = threadIdx.x;
  const float* px = x + (size_t)row * H_DIM;
  float4 v = *(const float4*)(px + t * 4);
  float s  = v.x + v.y + v.z + v.w;
  float ss = v.x * v.x + v.y * v.y + v.z * v.z + v.w * v.w;
  for (int off = 32; off > 0; off >>= 1) {
    s  += __shfl_down(s, off);
    ss += __shfl_down(ss, off);
  }
  __shared__ float red[8];
  __shared__ float stats[2];
  int wave = t >> 6, lane = t & 63;
  if (lane == 0) { red[wave] = s; red[4 + wave] = ss; }
  __syncthreads();
  if (t == 0) {
    float S  = red[0] + red[1] + red[2] + red[3];
    float SS = red[4] + red[5] + red[6] + red[7];
    float mu = S / H_DIM;
    float var = SS / H_DIM - mu * mu;
    stats[0] = mu;
    stats[1] = rsqrtf(var + 1e-5f);
  }
  __syncthreads();
  float mu = stats[0], rstd = stats[1];
  float4 g  = *(const float4*)(gamma + t * 4);
  float4 bt = *(const float4*)(beta + t * 4);
  __hip_bfloat16* po = out + (size_t)row * H_DIM + t * 4;
  po[0] = __float2bfloat16((v.x - mu) * rstd * g.x + bt.x);
  po[1] = __float2bfloat16((v.y - mu) * rstd * g.y + bt.y);
  po[2] = __float2bfloat16((v.z - mu) * rstd * g.z + bt.z);
  po[3] = __float2bfloat16((v.w - mu) * rstd * g.w + bt.w);
}

// ---------------- transpose+convert: in fp32 [R][C] -> out bf16 [C][R] ----------------
__global__ void transpose_bf16(const float* __restrict__ in,
                               __hip_bfloat16* __restrict__ out, int R, int C) {
  __shared__ float tile[32][33];
  int c0 = blockIdx.x * 32, r0 = blockIdx.y * 32;
  int tx = threadIdx.x, ty = threadIdx.y;   // (32, 8)
  for (int i = 0; i < 32; i += 8)
    tile[ty + i][tx] = in[(size_t)(r0 + ty + i) * C + c0 + tx];
  __syncthreads();
  for (int i = 0; i < 32; i += 8)
    out[(size_t)(c0 + ty + i) * R + r0 + tx] = __float2bfloat16(tile[tx][ty + i]);
}

// ---- W_B/W_C [2048][16] fp32 -> W_ext rows 2048..2079 (bf16, transposed) ----
__global__ __launch_bounds__(256) void wbc_transpose(const float* __restrict__ WB,
    const float* __restrict__ WC, __hip_bfloat16* __restrict__ Wext) {
  int tid = blockIdx.x * 256 + threadIdx.x;   // < 4096
  int c = tid & 31;
  int k0 = (tid >> 5) * 16;
  const float* W = (c < 16) ? WB : WC;
  int cc = c & 15;
  __hip_bfloat16* o = Wext + (size_t)(2048 + c) * D_DIM + k0;
  for (int kk = 0; kk < 16; ++kk)
    o[kk] = __float2bfloat16(W[(size_t)(k0 + kk) * N_STATE + cc]);
}

// ========== 256x256 4-phase counted-vmcnt bf16 MFMA GEMM (spill-free) =========
// Round-1 region-retirement schedule with the round-5 spill fix (512,1).
// 8 waves (2Mx4N), BK=64, LDS 128 KiB dbuf, XOR-swizzle via pre-swizzled src.
// Regions per buffer: A-lo rows 0-127 (read by wm=0 waves), A-hi rows 128-255
// (wm=1), B-lo cols 0-127 (wn<2), B-hi (wn>=2).  Last read: B* ph1, A* ph3.
// Stages: ph1 Ahi(kt+1)->nxt; ph2 Blo(kt+2)->cur; ph3 Bhi(kt+2)->cur;
// ph4 Alo(kt+2)->cur; vmcnt(6) at ph4 end (covers all of kt+1, leaves kt+2's
// 3 staged regions in flight).  Gates: barrier / lgkm(0) / setprio(1) / MFMA /
// setprio(0) / barrier — no sched_barrier (m141/m201 template).
template <int MODE>
__global__ __launch_bounds__(512, 1) void gemm256(
    const __hip_bfloat16* __restrict__ A, const __hip_bfloat16* __restrict__ Bt,
    void* __restrict__ C0, void* __restrict__ C1, int nsplit, int nlimit,
    int K, int lda, int ldb, int ldc, int ntn,
    const float* __restrict__ bias, const float* __restrict__ resid) {
  __shared__ __hip_bfloat16 lds[65536];   // 128 KiB
  const int t = threadIdx.x;
  const int nwg = gridDim.x;              // divisible by 8
  int bid = blockIdx.x;
  int wgid = (bid & 7) * (nwg >> 3) + (bid >> 3);   // XCD-contiguous sweep
  const int m0 = (wgid / ntn) * 256;
  const int n0 = (wgid % ntn) * 256;

  const int wave = t >> 6, lane = t & 63;
  const int wm = wave >> 2, wn = wave & 3;
  const int l16 = lane & 15, quad = lane >> 4;
  const int bh = wn >> 1;

  // staging: thread t -> row srow (0..63), slot cslot (0..7);
  // global chunk = cslot ^ (srow&7) (pre-swizzled source, linear LDS dest)
  const int srow = t >> 3, cslot = t & 7;
  const int cdata = cslot ^ (srow & 7);
  const __hip_bfloat16* Ast = A + (size_t)(m0 + srow) * lda + cdata * 8;
  const __hip_bfloat16* Bst = Bt + (size_t)(n0 + srow) * ldb + cdata * 8;
  const int stoff = srow * 64 + cslot * 8;          // elems

  // fragment read offsets; logical chunk q read at stored slot q^(l16&7)
  const int ch0 = quad ^ (l16 & 7);
  const int ch1 = ch0 ^ 4;
  const int aoff0 = wm * 8192 + l16 * 64 + ch0 * 8;
  const int aoff1 = wm * 8192 + l16 * 64 + ch1 * 8;
  const int boff0 = 16384 + bh * 8192 + ((wn & 1) * 64 + l16) * 64 + ch0 * 8;
  const int boff1 = 16384 + bh * 8192 + ((wn & 1) * 64 + l16) * 64 + ch1 * 8;

  const int NT = K >> 6;

#define STAGE_HT(dstb, mat, h, ktX) do {                                        \
    const __hip_bfloat16* g_ = ((mat) ? Bst : Ast)                              \
        + (size_t)((h) * 128) * ((mat) ? ldb : lda) + (size_t)(ktX) * 64;       \
    __hip_bfloat16* l_ = &lds[(dstb) + (mat) * 16384 + (h) * 8192 + stoff];     \
    gl_lds16(g_, l_);                                                           \
    gl_lds16(g_ + (size_t)64 * ((mat) ? ldb : lda), l_ + 4096);                 \
  } while (0)

#define RD_A(aP, i0, db_) do {                                                  \
    aP[0][0] = *(const bf16x8*)&lds[(db_) + aoff0 + (i0) * 1024];               \
    aP[0][1] = *(const bf16x8*)&lds[(db_) + aoff1 + (i0) * 1024];               \
    aP[1][0] = *(const bf16x8*)&lds[(db_) + aoff0 + ((i0) + 1) * 1024];         \
    aP[1][1] = *(const bf16x8*)&lds[(db_) + aoff1 + ((i0) + 1) * 1024];         \
  } while (0)

#define RD_B(db_) do {                                                          \
    _Pragma("unroll") for (int j = 0; j < 4; ++j) {                             \
      bB0[j] = *(const bf16x8*)&lds[(db_) + boff0 + j * 1024];                  \
      bB1[j] = *(const bf16x8*)&lds[(db_) + boff1 + j * 1024];                  \
    }                                                                           \
  } while (0)

#define MFMA_PAIR(aP, i0) do {                                                  \
    _Pragma("unroll") for (int j = 0; j < 4; ++j) {                             \
      acc[i0][j] = __builtin_amdgcn_mfma_f32_16x16x32_bf16(                     \
          aP[0][0], bB0[j], acc[i0][j], 0, 0, 0);                               \
      acc[i0][j] = __builtin_amdgcn_mfma_f32_16x16x32_bf16(                     \
          aP[0][1], bB1[j], acc[i0][j], 0, 0, 0);                               \
      acc[(i0) + 1][j] = __builtin_amdgcn_mfma_f32_16x16x32_bf16(               \
          aP[1][0], bB0[j], acc[(i0) + 1][j], 0, 0, 0);                         \
      acc[(i0) + 1][j] = __builtin_amdgcn_mfma_f32_16x16x32_bf16(               \
          aP[1][1], bB1[j], acc[(i0) + 1][j], 0, 0, 0);                         \
    }                                                                           \
  } while (0)

#define PH_GATE() do {                                                          \
    __builtin_amdgcn_s_barrier();                                               \
    asm volatile("s_waitcnt lgkmcnt(0)" ::: "memory");                          \
    __builtin_amdgcn_s_setprio(1);                                              \
  } while (0)

#define PH_END() do {                                                           \
    __builtin_amdgcn_s_setprio(0);                                              \
    __builtin_amdgcn_s_barrier();                                               \
  } while (0)

  f32x4 acc[8][4] = {};
  bf16x8 bB0[4], bB1[4];
  bf16x8 a01[2][2], a23[2][2], a45[2][2], a67[2][2];

  // ---- prologue: K-tile 0 fully + K-tile 1 first 3 regions ----
  STAGE_HT(0, 1, 0, 0);        // kt0 B-lo
  STAGE_HT(0, 1, 1, 0);        // kt0 B-hi
  STAGE_HT(0, 0, 0, 0);        // kt0 A-lo
  STAGE_HT(0, 0, 1, 0);        // kt0 A-hi
  STAGE_HT(32768, 1, 0, 1);    // kt1 B-lo
  STAGE_HT(32768, 1, 1, 1);    // kt1 B-hi
  STAGE_HT(32768, 0, 0, 1);    // kt1 A-lo
  asm volatile("s_waitcnt vmcnt(6)" ::: "memory");   // kt0's 8 loads landed
  __builtin_amdgcn_s_barrier();

  for (int kt = 0; kt < NT; ++kt) {
    const int db32 = (kt & 1) << 15;
    const int dn32 = db32 ^ 32768;
    const bool p1 = (kt + 1 < NT);
    const bool p2 = (kt + 2 < NT);
    // ---- ph1: read all B + A M0-1; stage next-tile A-hi ----
    RD_B(db32);
    RD_A(a01, 0, db32);
    if (p1) STAGE_HT(dn32, 0, 1, kt + 1);
    PH_GATE();
    MFMA_PAIR(a01, 0);
    PH_END();
    // ---- ph2: read A M2-5; stage kt+2 B-lo ----
    RD_A(a23, 2, db32);
    RD_A(a45, 4, db32);
    if (p2) STAGE_HT(db32, 1, 0, kt + 2);
    PH_GATE();
    MFMA_PAIR(a23, 2);
    PH_END();
    // ---- ph3: read A M6-7; stage kt+2 B-hi ----
    RD_A(a67, 6, db32);
    if (p2) STAGE_HT(db32, 1, 1, kt + 2);
    PH_GATE();
    MFMA_PAIR(a45, 4);
    PH_END();
    // ---- ph4: stage kt+2 A-lo; MFMA a67; counted vmcnt ----
    if (p2) STAGE_HT(db32, 0, 0, kt + 2);
    __builtin_amdgcn_s_barrier();
    __builtin_amdgcn_s_setprio(1);
    MFMA_PAIR(a67, 6);
    __builtin_amdgcn_s_setprio(0);
    if (p2) {
      asm volatile("s_waitcnt vmcnt(6)" ::: "memory");  // kt+1 fully landed
    } else {
      asm volatile("s_waitcnt vmcnt(0)" ::: "memory");  // tail drain
    }
    __builtin_amdgcn_s_barrier();
  }

  // ---- epilogue ----
  const int row_base = m0 + wm * 128;
  const int col_base = n0 + wn * 64;
#pragma unroll
  for (int i = 0; i < 8; ++i) {
    const int row0 = row_base + i * 16 + quad * 4;   // C/D: col=lane&15, row=quad*4+reg
#pragma unroll
    for (int j = 0; j < 4; ++j) {
      const int col = col_base + j * 16 + l16;
      f32x4 v = acc[i][j];
      if (MODE == 0) {
#pragma unroll
        for (int r = 0; r < 4; ++r) {
          size_t idx = (size_t)(row0 + r) * ldc + col;
          ((float*)C0)[idx] = v[r] + resid[idx];
        }
      } else if (MODE == 1) {
        bool mainc = (col < nsplit);
        __hip_bfloat16* cb = mainc ? (__hip_bfloat16*)C0 : (__hip_bfloat16*)C1;
        int ccol = mainc ? col : col - nsplit;
#pragma unroll
        for (int r = 0; r < 4; ++r)
          cb[(size_t)(row0 + r) * ldc + ccol] = __float2bfloat16(v[r]);
      } else {
        if (col < nsplit) {
          float bb = bias[col];
#pragma unroll
          for (int r = 0; r < 4; ++r)
            ((__hip_bfloat16*)C0)[(size_t)(row0 + r) * ldc + col] =
                __float2bfloat16(softplusf_(v[r] + bb));
        } else if (col < nlimit) {
#pragma unroll
          for (int r = 0; r < 4; ++r)
            ((float*)C1)[(size_t)(row0 + r) * 128 + (col - nsplit)] = v[r];
        }
      }
    }
  }
#undef STAGE_HT
#undef RD_A
#undef RD_B
#undef MFMA_PAIR
#undef PH_GATE
#undef PH_END
}

// ---------------- 128x128 bf16 MFMA GEMM (round-3 proven; GEMM3) --------------
#define BM 128
#define BN 128
#define BK 64

template <int MODE>
__global__ __launch_bounds__(256) void gemm_bf16(
    const __hip_bfloat16* __restrict__ A, const __hip_bfloat16* __restrict__ Bt,
    void* __restrict__ C0, void* __restrict__ C1, int nsplit,
    int K, int lda, int ldb, int ldc, int gx,
    const float* __restrict__ bias, const float* __restrict__ resid) {
  __shared__ __hip_bfloat16 As[2 * BM * BK];   // 32 KB (double-buffered)
  __shared__ __hip_bfloat16 Bs[2 * BN * BK];   // 32 KB
  int t = threadIdx.x;
  int bid = blockIdx.x;
  int nsup = gx << 3;
  int super = bid / nsup;
  int rem = bid - super * nsup;
  int m0 = (super * 8 + (rem & 7)) * BM;
  int n0 = (rem >> 3) * BN;

  int wave = t >> 6, lane = t & 63;
  int quad = lane >> 4, l16 = lane & 15;
  int wm = (wave >> 1) * 64, wn = (wave & 1) * 64;

  f32x4 acc[4][4] = {};

  int srow  = t >> 3;            // 0..31
  int cslot = t & 7;
  int cdata = cslot ^ (srow & 7);
  const __hip_bfloat16* Ag[4];
  const __hip_bfloat16* Bg[4];
  int soff[4];
#pragma unroll
  for (int j = 0; j < 4; ++j) {
    Ag[j]  = A  + (size_t)(m0 + j * 32 + srow) * lda + cdata * 8;
    Bg[j]  = Bt + (size_t)(n0 + j * 32 + srow) * ldb + cdata * 8;
    soff[j] = (j * 32 + srow) * BK + cslot * 8;
  }

  const int NT = K / BK;
#pragma unroll
  for (int j = 0; j < 4; ++j) {
    gl_lds16(Ag[j], &As[soff[j]]);
    gl_lds16(Bg[j], &Bs[soff[j]]);
  }
  asm volatile("s_waitcnt vmcnt(0)" ::: "memory");
  __builtin_amdgcn_s_barrier();

  for (int kt = 0; kt < NT; ++kt) {
    const int cur = (kt & 1) * (BM * BK);
    const int nxt = cur ^ (BM * BK);
    if (kt + 1 < NT) {
      const int k1 = (kt + 1) * BK;
#pragma unroll
      for (int j = 0; j < 4; ++j) {
        gl_lds16(Ag[j] + k1, &As[nxt + soff[j]]);
        gl_lds16(Bg[j] + k1, &Bs[nxt + soff[j]]);
      }
    }
#pragma unroll
    for (int s = 0; s < 2; ++s) {
      int cs = ((s * 4 + quad) ^ (l16 & 7)) * 8;
      bf16x8 af[4], bf_[4];
#pragma unroll
      for (int i = 0; i < 4; ++i) {
        af[i]  = *(const bf16x8*)&As[cur + (wm + i * 16 + l16) * BK + cs];
        bf_[i] = *(const bf16x8*)&Bs[cur + (wn + i * 16 + l16) * BK + cs];
      }
#pragma unroll
      for (int i = 0; i < 4; ++i)
#pragma unroll
        for (int j = 0; j < 4; ++j)
          acc[i][j] = __builtin_amdgcn_mfma_f32_16x16x32_bf16(af[i], bf_[j], acc[i][j], 0, 0, 0);
    }
    asm volatile("s_waitcnt vmcnt(0)" ::: "memory");
    __builtin_amdgcn_s_barrier();
  }

#pragma unroll
  for (int i = 0; i < 4; ++i) {
    int row0 = m0 + wm + i * 16 + quad * 4;
#pragma unroll
    for (int j = 0; j < 4; ++j) {
      int col = n0 + wn + j * 16 + l16;
      f32x4 v = acc[i][j];
      if (MODE == 0) {
#pragma unroll
        for (int r = 0; r < 4; ++r) {
          size_t idx = (size_t)(row0 + r) * ldc + col;
          ((float*)C0)[idx] = v[r] + resid[idx];
        }
      } else if (MODE == 1) {
        bool mainc = (col < nsplit);
        __hip_bfloat16* cb = mainc ? (__hip_bfloat16*)C0 : (__hip_bfloat16*)C1;
        int ccol = mainc ? col : col - nsplit;
#pragma unroll
        for (int r = 0; r < 4; ++r)
          cb[(size_t)(row0 + r) * ldc + ccol] = __float2bfloat16(v[r]);
      } else {
        if (col < nsplit) {
          float bb = bias[col];
#pragma unroll
          for (int r = 0; r < 4; ++r)
            ((__hip_bfloat16*)C0)[(size_t)(row0 + r) * ldc + col] =
                __float2bfloat16(softplusf_(v[r] + bb));
        } else {
#pragma unroll
          for (int r = 0; r < 4; ++r)
            ((float*)C1)[(size_t)(row0 + r) * 128 + (col - nsplit)] = v[r];
        }
      }
    }
  }
}

// ---------------- depthwise conv(3) + SiLU, bf16 in/out ----------------
__global__ __launch_bounds__(256) void conv_silu_kernel(const __hip_bfloat16* __restrict__ xb,
    const float* __restrict__ cw, const float* __restrict__ cb,
    __hip_bfloat16* __restrict__ xbc) {
  size_t i2 = (size_t)blockIdx.x * 256 + threadIdx.x;  // pair index < TOKENS*D_DIM/2
  int dp = (int)(i2 & (D_DIM / 2 - 1));
  size_t tok = i2 >> 10;
  int l = (int)(tok & (L_DIM - 1));
  int d = dp * 2;
  const __hip_bfloat162* base = (const __hip_bfloat162*)xb + i2;
  __hip_bfloat162 cc = base[0];
  float v0 = cw[d * 3 + 1] * __bfloat162float(cc.x) + cb[d];
  float v1 = cw[d * 3 + 4] * __bfloat162float(cc.y) + cb[d + 1];
  if (l > 0) {
    __hip_bfloat162 pm = base[-(D_DIM / 2)];
    v0 += cw[d * 3 + 0] * __bfloat162float(pm.x);
    v1 += cw[d * 3 + 3] * __bfloat162float(pm.y);
  }
  if (l < L_DIM - 1) {
    __hip_bfloat162 pp = base[D_DIM / 2];
    v0 += cw[d * 3 + 2] * __bfloat162float(pp.x);
    v1 += cw[d * 3 + 5] * __bfloat162float(pp.y);
  }
  v0 = v0 * sigmoidf_(v0);
  v1 = v1 * sigmoidf_(v1);
  __hip_bfloat162 o;
  o.x = __float2bfloat16(v0);
  o.y = __float2bfloat16(v1);
  ((__hip_bfloat162*)xbc)[i2] = o;
}

// ---------------- chunked scan phase 1: one lane per (b,chunk,d), h[16] in regs ----
// BiCi layout: [tok][128] fp32, B = cols 0..15, C = cols 16..31.
__global__ __launch_bounds__(256) void scan1_kernel(const __hip_bfloat16* __restrict__ dt,
    const __hip_bfloat16* __restrict__ xbc, const float* __restrict__ BiCi,
    const float* __restrict__ A_log, float* __restrict__ hfin,
    float* __restrict__ dtsum) {
  __shared__ float Bsh[LC * N_STATE];   // 4 KB
  int t = threadIdx.x;
  int d = blockIdx.x * 256 + t;
  int c = blockIdx.y, b = blockIdx.z;
  size_t base = (size_t)b * L_DIM + (size_t)c * LC;
  for (int idx = t; idx < LC * 4; idx += 256) {
    int row = idx >> 2, q = idx & 3;
    ((float4*)Bsh)[row * 4 + q] = *(const float4*)&BiCi[(base + row) * 128 + q * 4];
  }
  float Aneg[N_STATE];
  {
    const float4* Ap = (const float4*)(A_log + (size_t)d * N_STATE);
#pragma unroll
    for (int q = 0; q < 4; ++q) {
      float4 av = Ap[q];
      Aneg[4 * q + 0] = -__expf(av.x);
      Aneg[4 * q + 1] = -__expf(av.y);
      Aneg[4 * q + 2] = -__expf(av.z);
      Aneg[4 * q + 3] = -__expf(av.w);
    }
  }
  __syncthreads();
  const __hip_bfloat16* dtp = dt + base * D_DIM + d;
  const __hip_bfloat16* xp = xbc + base * D_DIM + d;
  float h[N_STATE];
#pragma unroll
  for (int n = 0; n < N_STATE; ++n) h[n] = 0.f;
  float ds = 0.f;
  float dtv = __bfloat162float(dtp[0]), xv = __bfloat162float(xp[0]);
  for (int i = 0; i < LC; ++i) {
    int ip = (i < LC - 1) ? i + 1 : i;   // clamped prefetch
    float dt2 = __bfloat162float(dtp[(size_t)ip * D_DIM]);
    float x2  = __bfloat162float(xp[(size_t)ip * D_DIM]);
    float dtx = dtv * xv;
    ds += dtv;
    const float4* Brow = (const float4*)&Bsh[i * N_STATE];
#pragma unroll
    for (int q = 0; q < 4; ++q) {
      float4 bv = Brow[q];
      h[4*q+0] = __expf(dtv * Aneg[4*q+0]) * h[4*q+0] + dtx * bv.x;
      h[4*q+1] = __expf(dtv * Aneg[4*q+1]) * h[4*q+1] + dtx * bv.y;
      h[4*q+2] = __expf(dtv * Aneg[4*q+2]) * h[4*q+2] + dtx * bv.z;
      h[4*q+3] = __expf(dtv * Aneg[4*q+3]) * h[4*q+3] + dtx * bv.w;
    }
    dtv = dt2; xv = x2;
  }
  float* ho = hfin + (((size_t)b * CH + c) * D_DIM + d) * N_STATE;
#pragma unroll
  for (int q = 0; q < 4; ++q) {
    float4 v; v.x = h[4*q]; v.y = h[4*q+1]; v.z = h[4*q+2]; v.w = h[4*q+3];
    ((float4*)ho)[q] = v;
  }
  dtsum[((size_t)b * CH + c) * D_DIM + d] = ds;
}

// ---------------- chunked scan phase 2: combine across chunks ----------------
__global__ __launch_bounds__(256) void scan2_kernel(const float* __restrict__ hfin,
    const float* __restrict__ dtsum, const float* __restrict__ A_log,
    float* __restrict__ hstart) {
  int tid = blockIdx.x * 256 + threadIdx.x;   // < B*D*N = 131072
  int n = tid & 15;
  int d = (tid >> 4) & (D_DIM - 1);
  int b = tid >> 15;
  float Aneg = -__expf(A_log[d * N_STATE + n]);
  float run = 0.f;
  for (int c = 0; c < CH; ++c) {
    size_t o = (((size_t)b * CH + c) * D_DIM + d) * N_STATE + n;
    hstart[o] = run;
    run = __expf(Aneg * dtsum[((size_t)b * CH + c) * D_DIM + d]) * run + hfin[o];
  }
}

// ---------------- chunked scan phase 3: rescan + fused gate, h[16] in regs ----------
__global__ __launch_bounds__(256) void scan3_kernel(const __hip_bfloat16* __restrict__ dt,
    const __hip_bfloat16* __restrict__ xbc, const float* __restrict__ BiCi,
    const float* __restrict__ A_log,
    const float* __restrict__ hstart, const __hip_bfloat16* __restrict__ z,
    const float* __restrict__ Dp, __hip_bfloat16* __restrict__ yo) {
  __shared__ float Bsh[LC * N_STATE];   // 4 KB
  __shared__ float Csh[LC * N_STATE];   // 4 KB
  int t = threadIdx.x;
  int d = blockIdx.x * 256 + t;
  int c = blockIdx.y, b = blockIdx.z;
  size_t base = (size_t)b * L_DIM + (size_t)c * LC;
  for (int idx = t; idx < LC * 4; idx += 256) {
    int row = idx >> 2, q = idx & 3;
    ((float4*)Bsh)[row * 4 + q] = *(const float4*)&BiCi[(base + row) * 128 + q * 4];
    ((float4*)Csh)[row * 4 + q] = *(const float4*)&BiCi[(base + row) * 128 + 16 + q * 4];
  }
  float Aneg[N_STATE];
  {
    const float4* Ap = (const float4*)(A_log + (size_t)d * N_STATE);
#pragma unroll
    for (int q = 0; q < 4; ++q) {
      float4 av = Ap[q];
      Aneg[4 * q + 0] = -__expf(av.x);
      Aneg[4 * q + 1] = -__expf(av.y);
      Aneg[4 * q + 2] = -__expf(av.z);
      Aneg[4 * q + 3] = -__expf(av.w);
    }
  }
  float h[N_STATE];
  {
    const float4* hs = (const float4*)(hstart + (((size_t)b * CH + c) * D_DIM + d) * N_STATE);
#pragma unroll
    for (int q = 0; q < 4; ++q) {
      float4 v = hs[q];
      h[4*q] = v.x; h[4*q+1] = v.y; h[4*q+2] = v.z; h[4*q+3] = v.w;
    }
  }
  float Dv = Dp[d];
  __syncthreads();
  const __hip_bfloat16* dtp = dt + base * D_DIM + d;
  const __hip_bfloat16* xp = xbc + base * D_DIM + d;
  const __hip_bfloat16* zp = z + base * D_DIM + d;
  __hip_bfloat16* yp = yo + base * D_DIM + d;
  float dtv = __bfloat162float(dtp[0]), xv = __bfloat162float(xp[0]);
  float zv = __bfloat162float(zp[0]);
  for (int i = 0; i < LC; ++i) {
    int ip = (i < LC - 1) ? i + 1 : i;   // clamped prefetch
    float dt2 = __bfloat162float(dtp[(size_t)ip * D_DIM]);
    float x2  = __bfloat162float(xp[(size_t)ip * D_DIM]);
    float z2  = __bfloat162float(zp[(size_t)ip * D_DIM]);
    float dtx = dtv * xv;
    const float4* Brow = (const float4*)&Bsh[i * N_STATE];
    const float4* Crow = (const float4*)&Csh[i * N_STATE];
    float yv = 0.f;
#pragma unroll
    for (int q = 0; q < 4; ++q) {
      float4 bv = Brow[q];
      float4 cv = Crow[q];
      h[4*q+0] = __expf(dtv * Aneg[4*q+0]) * h[4*q+0] + dtx * bv.x;
      h[4*q+1] = __expf(dtv * Aneg[4*q+1]) * h[4*q+1] + dtx * bv.y;
      h[4*q+2] = __expf(dtv * Aneg[4*q+2]) * h[4*q+2] + dtx * bv.z;
      h[4*q+3] = __expf(dtv * Aneg[4*q+3]) * h[4*q+3] + dtx * bv.w;
      yv += h[4*q+0] * cv.x + h[4*q+1] * cv.y + h[4*q+2] * cv.z + h[4*q+3] * cv.w;
    }
    float g = zv * sigmoidf_(zv);
    yp[(size_t)i * D_DIM] = __float2bfloat16((yv + Dv * xv) * g);
    dtv = dt2; xv = x2; zv = z2;
  }
}

extern "C" void kernel_launch(void* const* d_in, const int* in_sizes, int n_in,
                              void* d_out, int out_size, void* d_ws, size_t ws_size,
                              hipStream_t stream) {
  const float* x          = (const float*)d_in[0];
  const float* norm_scale = (const float*)d_in[1];
  const float* norm_bias  = (const float*)d_in[2];
  const float* W_in       = (const float*)d_in[3];
  const float* conv_w     = (const float*)d_in[4];
  const float* conv_b     = (const float*)d_in[5];
  const float* W_dt       = (const float*)d_in[6];
  const float* b_dt       = (const float*)d_in[7];
  const float* A_log      = (const float*)d_in[8];
  const float* D_param    = (const float*)d_in[9];
  const float* W_B        = (const float*)d_in[10];
  const float* W_C        = (const float*)d_in[11];
  const float* W_out      = (const float*)d_in[12];
  float* out = (float*)d_out;

  // Workspace layout (193 MB):
  //  S0 [  0, 16M): xn bf16 (dead after GEMM1) -> W_outT [0,4M)
  //  S1 [ 16, 48M): xb bf16 (GEMM1->conv) -> ybf bf16 (scan3 -> GEMM3)
  //  S2 [ 48, 80M): z bf16 (GEMM1->scan3)
  //  S3 [ 80,112M): xbc bf16 (conv->scan)
  //  S4 [112,144M): dt bf16 (GEMM2 main out -> scan)
  //     [144,148M): BiCi fp32 [8192][128] (GEMM2 split out -> scan)
  //     [148,157.5M): W_ext bf16 [2304][2048] (transposes -> GEMM2; rows 2080+ pad)
  //     [158,174M): hstart fp32 (16M, CH=32)
  //     [174,175M): dtsum fp32 (1M)
  //  S6 [177,185M): W_inT bf16 (dead after GEMM1) -> hfin fp32 [177,193M) (16M)
  const size_t MB = 1024 * 1024;
  const size_t NEEDED = 193 * MB;
  if (ws_size < NEEDED) return;   // diagnostic bail: ws too small

  char* ws = (char*)d_ws;
  __hip_bfloat16* xn     = (__hip_bfloat16*)(ws);
  __hip_bfloat16* W_outT = (__hip_bfloat16*)(ws);            // [0,4M) after xn dead
  __hip_bfloat16* xb     = (__hip_bfloat16*)(ws + 16 * MB);
  __hip_bfloat16* ybf    = (__hip_bfloat16*)(ws + 16 * MB);  // after conv
  __hip_bfloat16* z      = (__hip_bfloat16*)(ws + 48 * MB);
  __hip_bfloat16* xbc    = (__hip_bfloat16*)(ws + 80 * MB);
  __hip_bfloat16* dtY    = (__hip_bfloat16*)(ws + 112 * MB);
  float*          BiCi   = (float*)(ws + 144 * MB);
  __hip_bfloat16* W_ext  = (__hip_bfloat16*)(ws + 148 * MB);
  float*          hstart = (float*)(ws + 158 * MB);          // 16M
  float*          dtsum  = (float*)(ws + 174 * MB);          // 1M
  __hip_bfloat16* W_inT  = (__hip_bfloat16*)(ws + 177 * MB);
  float*          hfin   = (float*)(ws + 177 * MB);          // 16M after W_inT dead

  dim3 tb(32, 8);
  // 0. weight transpose+convert
  transpose_bf16<<<dim3(4096 / 32, 1024 / 32), tb, 0, stream>>>(W_in, W_inT, 1024, 4096);
  transpose_bf16<<<dim3(2048 / 32, 2048 / 32), tb, 0, stream>>>(W_dt, W_ext, 2048, 2048);
  wbc_transpose<<<16, 256, 0, stream>>>(W_B, W_C, W_ext);
  // 1. LayerNorm -> bf16
  ln_kernel<<<TOKENS, 256, 0, stream>>>(x, norm_scale, norm_bias, xn);
  // 2. merged [xb|z] = xn @ W_in  (MODE 1 split) — 4-phase 256², 512 blocks
  gemm256<1><<<(TOKENS / 256) * (4096 / 256), 512, 0, stream>>>(
      xn, W_inT, xb, z, D_DIM, 1 << 30, H_DIM, H_DIM, H_DIM, D_DIM, 4096 / 256,
      nullptr, nullptr);
  // (xn dead) convert W_out into S0
  transpose_bf16<<<dim3(1024 / 32, 2048 / 32), tb, 0, stream>>>(W_out, W_outT, 2048, 1024);
  // 3. depthwise conv + silu -> xbc bf16
  conv_silu_kernel<<<(TOKENS * D_DIM / 2) / 256, 256, 0, stream>>>(xb, conv_w, conv_b, xbc);
  // 4. fused: [dt | Bi | Ci] = xbc @ W_ext  (MODE 2) — 4-phase 256², 288 blocks
  gemm256<2><<<(TOKENS / 256) * (NEXT / 256), 512, 0, stream>>>(
      xbc, W_ext, dtY, BiCi, D_DIM, NLIM2, D_DIM, D_DIM, D_DIM, D_DIM, NEXT / 256,
      b_dt, nullptr);
  // 5. chunked scan: local -> combine -> rescan+gate (writes ybf, xb region dead)
  scan1_kernel<<<dim3(D_DIM / 256, CH, B_DIM), 256, 0, stream>>>(
      dtY, xbc, BiCi, A_log, hfin, dtsum);
  scan2_kernel<<<(B_DIM * D_DIM * N_STATE) / 256, 256, 0, stream>>>(
      hfin, dtsum, A_log, hstart);
  scan3_kernel<<<dim3(D_DIM / 256, CH, B_DIM), 256, 0, stream>>>(
      dtY, xbc, BiCi, A_log, hstart, z, D_param, ybf);
  // 6. out = x + y @ W_out   (MODE 0: fp32 + residual, 128x128 proven kernel)
  gemm_bf16<0><<<(H_DIM / BN) * (TOKENS / BM), 256, 0, stream>>>(
      ybf, W_outT, out, nullptr, 1 << 30, D_DIM, D_DIM, D_DIM, H_DIM, H_DIM / BN,
      nullptr, x);
}

// Round 7
// 571.787 us; speedup vs baseline: 1.1182x; 1.1182x over previous
//
#include <hip/hip_runtime.h>
#include <hip/hip_bf16.h>
#include <cstdint>
#include <cstddef>

#define B_DIM 4
#define L_DIM 2048
#define H_DIM 1024
#define D_DIM 2048
#define N_STATE 16
#define TOKENS (B_DIM * L_DIM)   // 8192
#define CH 32                    // scan chunks
#define LC (L_DIM / CH)          // 64 steps per chunk
#define NEXT 2176                // GEMM2 N: 2048 dt + 32 B/C + 96 pad (17 tiles of 128)

typedef __bf16 bf16x8 __attribute__((ext_vector_type(8)));
typedef float f32x4 __attribute__((ext_vector_type(4)));

__device__ __forceinline__ float sigmoidf_(float x) { return 1.f / (1.f + __expf(-x)); }
__device__ __forceinline__ float softplusf_(float x) {
  return fmaxf(x, 0.f) + log1pf(__expf(-fabsf(x)));
}
__device__ __forceinline__ void gl_lds16(const void* g, void* l) {
  __builtin_amdgcn_global_load_lds(
      (const __attribute__((address_space(1))) unsigned int*)g,
      (__attribute__((address_space(3))) unsigned int*)l, 16, 0, 0);
}

// ---- shared transpose body (fp32 [R][C] -> bf16 [C][R]), 256-thread block ----
__device__ __forceinline__ void do_transpose(const float* __restrict__ in,
    __hip_bfloat16* __restrict__ out, int R, int C, int c0, int r0, int t) {
  __shared__ float tile[32][33];
  int tx = t & 31, ty = t >> 5;   // 32 x 8
  for (int i = 0; i < 32; i += 8)
    tile[ty + i][tx] = in[(size_t)(r0 + ty + i) * C + c0 + tx];
  __syncthreads();
  for (int i = 0; i < 32; i += 8)
    out[(size_t)(c0 + ty + i) * R + r0 + tx] = __float2bfloat16(tile[tx][ty + i]);
}

// ---------------- merged prep: LN + W_in^T + W_dt^T + W_B/W_C pack -----------
// Block ranges: [0,8192) LN; [8192,12288) W_in transpose (128x32 tiles);
// [12288,16384) W_dt transpose (64x64 tiles); [16384,16400) wbc.
// Each block takes exactly one branch -> interior __syncthreads are uniform.
__global__ __launch_bounds__(256) void prep_kernel(
    const float* __restrict__ x, const float* __restrict__ gamma,
    const float* __restrict__ beta, __hip_bfloat16* __restrict__ xn,
    const float* __restrict__ W_in, __hip_bfloat16* __restrict__ W_inT,
    const float* __restrict__ W_dt, __hip_bfloat16* __restrict__ Wext,
    const float* __restrict__ WB, const float* __restrict__ WC) {
  int b = blockIdx.x;
  int t = threadIdx.x;
  if (b < TOKENS) {
    // ---- LayerNorm -> bf16, one block per token ----
    const float* px = x + (size_t)b * H_DIM;
    float4 v = *(const float4*)(px + t * 4);
    float s  = v.x + v.y + v.z + v.w;
    float ss = v.x * v.x + v.y * v.y + v.z * v.z + v.w * v.w;
    for (int off = 32; off > 0; off >>= 1) {
      s  += __shfl_down(s, off);
      ss += __shfl_down(ss, off);
    }
    __shared__ float red[8];
    __shared__ float stats[2];
    int wave = t >> 6, lane = t & 63;
    if (lane == 0) { red[wave] = s; red[4 + wave] = ss; }
    __syncthreads();
    if (t == 0) {
      float S  = red[0] + red[1] + red[2] + red[3];
      float SS = red[4] + red[5] + red[6] + red[7];
      float mu = S / H_DIM;
      float var = SS / H_DIM - mu * mu;
      stats[0] = mu;
      stats[1] = rsqrtf(var + 1e-5f);
    }
    __syncthreads();
    float mu = stats[0], rstd = stats[1];
    float4 g  = *(const float4*)(gamma + t * 4);
    float4 bt = *(const float4*)(beta + t * 4);
    __hip_bfloat16* po = xn + (size_t)b * H_DIM + t * 4;
    po[0] = __float2bfloat16((v.x - mu) * rstd * g.x + bt.x);
    po[1] = __float2bfloat16((v.y - mu) * rstd * g.y + bt.y);
    po[2] = __float2bfloat16((v.z - mu) * rstd * g.z + bt.z);
    po[3] = __float2bfloat16((v.w - mu) * rstd * g.w + bt.w);
    return;
  }
  b -= TOKENS;
  if (b < 4096) {   // W_in [1024][4096] -> W_inT [4096][1024]
    do_transpose(W_in, W_inT, 1024, 4096, (b & 127) * 32, (b >> 7) * 32, t);
    return;
  }
  b -= 4096;
  if (b < 4096) {   // W_dt [2048][2048] -> Wext rows 0..2047
    do_transpose(W_dt, Wext, 2048, 2048, (b & 63) * 32, (b >> 6) * 32, t);
    return;
  }
  b -= 4096;
  {   // W_B/W_C [2048][16] fp32 -> Wext rows 2048..2079 (transposed)
    int tid = b * 256 + t;   // < 4096
    int c = tid & 31;
    int k0 = (tid >> 5) * 16;
    const float* W = (c < 16) ? WB : WC;
    int cc = c & 15;
    __hip_bfloat16* o = Wext + (size_t)(2048 + c) * D_DIM + k0;
    for (int kk = 0; kk < 16; ++kk)
      o[kk] = __float2bfloat16(W[(size_t)(k0 + kk) * N_STATE + cc]);
  }
}

// ---------------- transpose+convert kernel (W_out, runs after GEMM1) ---------
__global__ void transpose_bf16(const float* __restrict__ in,
                               __hip_bfloat16* __restrict__ out, int R, int C) {
  __shared__ float tile[32][33];
  int c0 = blockIdx.x * 32, r0 = blockIdx.y * 32;
  int tx = threadIdx.x, ty = threadIdx.y;   // (32, 8)
  for (int i = 0; i < 32; i += 8)
    tile[ty + i][tx] = in[(size_t)(r0 + ty + i) * C + c0 + tx];
  __syncthreads();
  for (int i = 0; i < 32; i += 8)
    out[(size_t)(c0 + ty + i) * R + r0 + tx] = __float2bfloat16(tile[tx][ty + i]);
}

// ---------------- bf16 MFMA GEMM: C = A[M,K] @ Bt[N,K]^T ----------------
// 128x128 tile, BK=64, XOR-swizzled LDS (0 conflicts), XCD-aware 1D swizzle.
// T3-minimum double-buffer (m248v2): per K-step
//   stage(next -> buf^1) ; compute(buf) ; vmcnt(0) ; barrier
// One barrier per step; staging latency overlaps compute. Race-free: buf[cur]'s
// ds_reads complete before this step's MFMA (lgkm wait), which precedes the
// barrier; buf[cur] is only restaged after that barrier.
#define BM 128
#define BN 128
#define BK 64

template <int MODE>
__global__ __launch_bounds__(256) void gemm_bf16(
    const __hip_bfloat16* __restrict__ A, const __hip_bfloat16* __restrict__ Bt,
    void* __restrict__ C0, void* __restrict__ C1, int nsplit,
    int K, int lda, int ldb, int ldc, int gx,
    const float* __restrict__ bias, const float* __restrict__ resid) {
  __shared__ __hip_bfloat16 As[2 * BM * BK];   // 32 KB (double-buffered)
  __shared__ __hip_bfloat16 Bs[2 * BN * BK];   // 32 KB
  int t = threadIdx.x;
  // XCD-aware swizzle
  int bid = blockIdx.x;
  int nsup = gx << 3;
  int super = bid / nsup;
  int rem = bid - super * nsup;
  int m0 = (super * 8 + (rem & 7)) * BM;
  int n0 = (rem >> 3) * BN;

  int wave = t >> 6, lane = t & 63;
  int quad = lane >> 4, l16 = lane & 15;
  int wm = (wave >> 1) * 64, wn = (wave & 1) * 64;

  f32x4 acc[4][4] = {};

  // staging: 4 issues of 32 rows; thread t -> row j*32+(t>>3), slot (t&7);
  // global chunk cdata = cslot ^ (row&7) (XOR swizzle, pre-swizzled source).
  int srow  = t >> 3;            // 0..31
  int cslot = t & 7;
  int cdata = cslot ^ (srow & 7);
  const __hip_bfloat16* Ag[4];
  const __hip_bfloat16* Bg[4];
  int soff[4];
#pragma unroll
  for (int j = 0; j < 4; ++j) {
    Ag[j]  = A  + (size_t)(m0 + j * 32 + srow) * lda + cdata * 8;
    Bg[j]  = Bt + (size_t)(n0 + j * 32 + srow) * ldb + cdata * 8;
    soff[j] = (j * 32 + srow) * BK + cslot * 8;
  }

  const int NT = K / BK;
  // prologue: stage K-tile 0 into buffer 0
#pragma unroll
  for (int j = 0; j < 4; ++j) {
    gl_lds16(Ag[j], &As[soff[j]]);
    gl_lds16(Bg[j], &Bs[soff[j]]);
  }
  asm volatile("s_waitcnt vmcnt(0)" ::: "memory");
  __builtin_amdgcn_s_barrier();

  for (int kt = 0; kt < NT; ++kt) {
    const int cur = (kt & 1) * (BM * BK);
    const int nxt = cur ^ (BM * BK);
    if (kt + 1 < NT) {
      const int k1 = (kt + 1) * BK;
#pragma unroll
      for (int j = 0; j < 4; ++j) {
        gl_lds16(Ag[j] + k1, &As[nxt + soff[j]]);
        gl_lds16(Bg[j] + k1, &Bs[nxt + soff[j]]);
      }
    }
#pragma unroll
    for (int s = 0; s < 2; ++s) {
      int cs = ((s * 4 + quad) ^ (l16 & 7)) * 8;
      bf16x8 af[4], bf_[4];
#pragma unroll
      for (int i = 0; i < 4; ++i) {
        af[i]  = *(const bf16x8*)&As[cur + (wm + i * 16 + l16) * BK + cs];
        bf_[i] = *(const bf16x8*)&Bs[cur + (wn + i * 16 + l16) * BK + cs];
      }
#pragma unroll
      for (int i = 0; i < 4; ++i)
#pragma unroll
        for (int j = 0; j < 4; ++j)
          acc[i][j] = __builtin_amdgcn_mfma_f32_16x16x32_bf16(af[i], bf_[j], acc[i][j], 0, 0, 0);
    }
    asm volatile("s_waitcnt vmcnt(0)" ::: "memory");
    __builtin_amdgcn_s_barrier();
  }

#pragma unroll
  for (int i = 0; i < 4; ++i) {
    int row0 = m0 + wm + i * 16 + quad * 4;   // C/D: col=lane&15, row=quad*4+reg
#pragma unroll
    for (int j = 0; j < 4; ++j) {
      int col = n0 + wn + j * 16 + l16;
      f32x4 v = acc[i][j];
      if (MODE == 0) {
#pragma unroll
        for (int r = 0; r < 4; ++r) {
          size_t idx = (size_t)(row0 + r) * ldc + col;
          ((float*)C0)[idx] = v[r] + resid[idx];
        }
      } else if (MODE == 1) {
        bool mainc = (col < nsplit);
        __hip_bfloat16* cb = mainc ? (__hip_bfloat16*)C0 : (__hip_bfloat16*)C1;
        int ccol = mainc ? col : col - nsplit;
#pragma unroll
        for (int r = 0; r < 4; ++r)
          cb[(size_t)(row0 + r) * ldc + ccol] = __float2bfloat16(v[r]);
      } else {
        if (col < nsplit) {
          float bb = bias[col];
#pragma unroll
          for (int r = 0; r < 4; ++r)
            ((__hip_bfloat16*)C0)[(size_t)(row0 + r) * ldc + col] =
                __float2bfloat16(softplusf_(v[r] + bb));
        } else {
#pragma unroll
          for (int r = 0; r < 4; ++r)
            ((float*)C1)[(size_t)(row0 + r) * 128 + (col - nsplit)] = v[r];
        }
      }
    }
  }
}

// ---------------- depthwise conv(3) + SiLU, bf16 in/out ----------------
__global__ __launch_bounds__(256) void conv_silu_kernel(const __hip_bfloat16* __restrict__ xb,
    const float* __restrict__ cw, const float* __restrict__ cb,
    __hip_bfloat16* __restrict__ xbc) {
  size_t i2 = (size_t)blockIdx.x * 256 + threadIdx.x;  // pair index < TOKENS*D_DIM/2
  int dp = (int)(i2 & (D_DIM / 2 - 1));
  size_t tok = i2 >> 10;
  int l = (int)(tok & (L_DIM - 1));
  int d = dp * 2;
  const __hip_bfloat162* base = (const __hip_bfloat162*)xb + i2;
  __hip_bfloat162 cc = base[0];
  float v0 = cw[d * 3 + 1] * __bfloat162float(cc.x) + cb[d];
  float v1 = cw[d * 3 + 4] * __bfloat162float(cc.y) + cb[d + 1];
  if (l > 0) {
    __hip_bfloat162 pm = base[-(D_DIM / 2)];
    v0 += cw[d * 3 + 0] * __bfloat162float(pm.x);
    v1 += cw[d * 3 + 3] * __bfloat162float(pm.y);
  }
  if (l < L_DIM - 1) {
    __hip_bfloat162 pp = base[D_DIM / 2];
    v0 += cw[d * 3 + 2] * __bfloat162float(pp.x);
    v1 += cw[d * 3 + 5] * __bfloat162float(pp.y);
  }
  v0 = v0 * sigmoidf_(v0);
  v1 = v1 * sigmoidf_(v1);
  __hip_bfloat162 o;
  o.x = __float2bfloat16(v0);
  o.y = __float2bfloat16(v1);
  ((__hip_bfloat162*)xbc)[i2] = o;
}

// ---------------- chunked scan phase 1: one lane per (b,chunk,d), h[16] in regs ----
// BiCi layout: [tok][128] fp32, B = cols 0..15, C = cols 16..31.
__global__ __launch_bounds__(256) void scan1_kernel(const __hip_bfloat16* __restrict__ dt,
    const __hip_bfloat16* __restrict__ xbc, const float* __restrict__ BiCi,
    const float* __restrict__ A_log, float* __restrict__ hfin,
    float* __restrict__ dtsum) {
  __shared__ float Bsh[LC * N_STATE];   // 4 KB
  int t = threadIdx.x;
  int d = blockIdx.x * 256 + t;
  int c = blockIdx.y, b = blockIdx.z;
  size_t base = (size_t)b * L_DIM + (size_t)c * LC;
  for (int idx = t; idx < LC * 4; idx += 256) {
    int row = idx >> 2, q = idx & 3;
    ((float4*)Bsh)[row * 4 + q] = *(const float4*)&BiCi[(base + row) * 128 + q * 4];
  }
  float Aneg[N_STATE];
  {
    const float4* Ap = (const float4*)(A_log + (size_t)d * N_STATE);
#pragma unroll
    for (int q = 0; q < 4; ++q) {
      float4 av = Ap[q];
      Aneg[4 * q + 0] = -__expf(av.x);
      Aneg[4 * q + 1] = -__expf(av.y);
      Aneg[4 * q + 2] = -__expf(av.z);
      Aneg[4 * q + 3] = -__expf(av.w);
    }
  }
  __syncthreads();
  const __hip_bfloat16* dtp = dt + base * D_DIM + d;
  const __hip_bfloat16* xp = xbc + base * D_DIM + d;
  float h[N_STATE];
#pragma unroll
  for (int n = 0; n < N_STATE; ++n) h[n] = 0.f;
  float ds = 0.f;
  float dtv = __bfloat162float(dtp[0]), xv = __bfloat162float(xp[0]);
  for (int i = 0; i < LC; ++i) {
    int ip = (i < LC - 1) ? i + 1 : i;   // clamped prefetch
    float dt2 = __bfloat162float(dtp[(size_t)ip * D_DIM]);
    float x2  = __bfloat162float(xp[(size_t)ip * D_DIM]);
    float dtx = dtv * xv;
    ds += dtv;
    const float4* Brow = (const float4*)&Bsh[i * N_STATE];
#pragma unroll
    for (int q = 0; q < 4; ++q) {
      float4 bv = Brow[q];
      h[4*q+0] = __expf(dtv * Aneg[4*q+0]) * h[4*q+0] + dtx * bv.x;
      h[4*q+1] = __expf(dtv * Aneg[4*q+1]) * h[4*q+1] + dtx * bv.y;
      h[4*q+2] = __expf(dtv * Aneg[4*q+2]) * h[4*q+2] + dtx * bv.z;
      h[4*q+3] = __expf(dtv * Aneg[4*q+3]) * h[4*q+3] + dtx * bv.w;
    }
    dtv = dt2; xv = x2;
  }
  float* ho = hfin + (((size_t)b * CH + c) * D_DIM + d) * N_STATE;
#pragma unroll
  for (int q = 0; q < 4; ++q) {
    float4 v; v.x = h[4*q]; v.y = h[4*q+1]; v.z = h[4*q+2]; v.w = h[4*q+3];
    ((float4*)ho)[q] = v;
  }
  dtsum[((size_t)b * CH + c) * D_DIM + d] = ds;
}

// ---------------- chunked scan phase 2: combine across chunks ----------------
__global__ __launch_bounds__(256) void scan2_kernel(const float* __restrict__ hfin,
    const float* __restrict__ dtsum, const float* __restrict__ A_log,
    float* __restrict__ hstart) {
  int tid = blockIdx.x * 256 + threadIdx.x;   // < B*D*N = 131072
  int n = tid & 15;
  int d = (tid >> 4) & (D_DIM - 1);
  int b = tid >> 15;
  float Aneg = -__expf(A_log[d * N_STATE + n]);
  float run = 0.f;
  for (int c = 0; c < CH; ++c) {
    size_t o = (((size_t)b * CH + c) * D_DIM + d) * N_STATE + n;
    hstart[o] = run;
    run = __expf(Aneg * dtsum[((size_t)b * CH + c) * D_DIM + d]) * run + hfin[o];
  }
}

// ---------------- chunked scan phase 3: rescan + fused gate, h[16] in regs ----------
__global__ __launch_bounds__(256) void scan3_kernel(const __hip_bfloat16* __restrict__ dt,
    const __hip_bfloat16* __restrict__ xbc, const float* __restrict__ BiCi,
    const float* __restrict__ A_log,
    const float* __restrict__ hstart, const __hip_bfloat16* __restrict__ z,
    const float* __restrict__ Dp, __hip_bfloat16* __restrict__ yo) {
  __shared__ float Bsh[LC * N_STATE];   // 4 KB
  __shared__ float Csh[LC * N_STATE];   // 4 KB
  int t = threadIdx.x;
  int d = blockIdx.x * 256 + t;
  int c = blockIdx.y, b = blockIdx.z;
  size_t base = (size_t)b * L_DIM + (size_t)c * LC;
  for (int idx = t; idx < LC * 4; idx += 256) {
    int row = idx >> 2, q = idx & 3;
    ((float4*)Bsh)[row * 4 + q] = *(const float4*)&BiCi[(base + row) * 128 + q * 4];
    ((float4*)Csh)[row * 4 + q] = *(const float4*)&BiCi[(base + row) * 128 + 16 + q * 4];
  }
  float Aneg[N_STATE];
  {
    const float4* Ap = (const float4*)(A_log + (size_t)d * N_STATE);
#pragma unroll
    for (int q = 0; q < 4; ++q) {
      float4 av = Ap[q];
      Aneg[4 * q + 0] = -__expf(av.x);
      Aneg[4 * q + 1] = -__expf(av.y);
      Aneg[4 * q + 2] = -__expf(av.z);
      Aneg[4 * q + 3] = -__expf(av.w);
    }
  }
  float h[N_STATE];
  {
    const float4* hs = (const float4*)(hstart + (((size_t)b * CH + c) * D_DIM + d) * N_STATE);
#pragma unroll
    for (int q = 0; q < 4; ++q) {
      float4 v = hs[q];
      h[4*q] = v.x; h[4*q+1] = v.y; h[4*q+2] = v.z; h[4*q+3] = v.w;
    }
  }
  float Dv = Dp[d];
  __syncthreads();
  const __hip_bfloat16* dtp = dt + base * D_DIM + d;
  const __hip_bfloat16* xp = xbc + base * D_DIM + d;
  const __hip_bfloat16* zp = z + base * D_DIM + d;
  __hip_bfloat16* yp = yo + base * D_DIM + d;
  float dtv = __bfloat162float(dtp[0]), xv = __bfloat162float(xp[0]);
  float zv = __bfloat162float(zp[0]);
  for (int i = 0; i < LC; ++i) {
    int ip = (i < LC - 1) ? i + 1 : i;   // clamped prefetch
    float dt2 = __bfloat162float(dtp[(size_t)ip * D_DIM]);
    float x2  = __bfloat162float(xp[(size_t)ip * D_DIM]);
    float z2  = __bfloat162float(zp[(size_t)ip * D_DIM]);
    float dtx = dtv * xv;
    const float4* Brow = (const float4*)&Bsh[i * N_STATE];
    const float4* Crow = (const float4*)&Csh[i * N_STATE];
    float yv = 0.f;
#pragma unroll
    for (int q = 0; q < 4; ++q) {
      float4 bv = Brow[q];
      float4 cv = Crow[q];
      h[4*q+0] = __expf(dtv * Aneg[4*q+0]) * h[4*q+0] + dtx * bv.x;
      h[4*q+1] = __expf(dtv * Aneg[4*q+1]) * h[4*q+1] + dtx * bv.y;
      h[4*q+2] = __expf(dtv * Aneg[4*q+2]) * h[4*q+2] + dtx * bv.z;
      h[4*q+3] = __expf(dtv * Aneg[4*q+3]) * h[4*q+3] + dtx * bv.w;
      yv += h[4*q+0] * cv.x + h[4*q+1] * cv.y + h[4*q+2] * cv.z + h[4*q+3] * cv.w;
    }
    float g = zv * sigmoidf_(zv);
    yp[(size_t)i * D_DIM] = __float2bfloat16((yv + Dv * xv) * g);
    dtv = dt2; xv = x2; zv = z2;
  }
}

extern "C" void kernel_launch(void* const* d_in, const int* in_sizes, int n_in,
                              void* d_out, int out_size, void* d_ws, size_t ws_size,
                              hipStream_t stream) {
  const float* x          = (const float*)d_in[0];
  const float* norm_scale = (const float*)d_in[1];
  const float* norm_bias  = (const float*)d_in[2];
  const float* W_in       = (const float*)d_in[3];
  const float* conv_w     = (const float*)d_in[4];
  const float* conv_b     = (const float*)d_in[5];
  const float* W_dt       = (const float*)d_in[6];
  const float* b_dt       = (const float*)d_in[7];
  const float* A_log      = (const float*)d_in[8];
  const float* D_param    = (const float*)d_in[9];
  const float* W_B        = (const float*)d_in[10];
  const float* W_C        = (const float*)d_in[11];
  const float* W_out      = (const float*)d_in[12];
  float* out = (float*)d_out;

  // Workspace layout (193 MB):
  //  S0 [  0, 16M): xn bf16 (dead after GEMM1) -> W_outT [0,4M)
  //  S1 [ 16, 48M): xb bf16 (GEMM1->conv) -> ybf bf16 (scan3 -> GEMM3)
  //  S2 [ 48, 80M): z bf16 (GEMM1->scan3)
  //  S3 [ 80,112M): xbc bf16 (conv->scan)
  //  S4 [112,144M): dt bf16 (GEMM2 main out -> scan)
  //     [144,148M): BiCi fp32 [8192][128] (GEMM2 split out -> scan)
  //     [148,157M): W_ext bf16 [2176][2048] (transposes -> GEMM2)
  //     [158,174M): hstart fp32 (16M, CH=32)
  //     [174,175M): dtsum fp32 (1M)
  //  S6 [177,185M): W_inT bf16 (dead after GEMM1) -> hfin fp32 [177,193M) (16M)
  const size_t MB = 1024 * 1024;
  const size_t NEEDED = 193 * MB;
  if (ws_size < NEEDED) return;   // diagnostic bail: ws too small

  char* ws = (char*)d_ws;
  __hip_bfloat16* xn     = (__hip_bfloat16*)(ws);
  __hip_bfloat16* W_outT = (__hip_bfloat16*)(ws);            // [0,4M) after xn dead
  __hip_bfloat16* xb     = (__hip_bfloat16*)(ws + 16 * MB);
  __hip_bfloat16* ybf    = (__hip_bfloat16*)(ws + 16 * MB);  // after conv
  __hip_bfloat16* z      = (__hip_bfloat16*)(ws + 48 * MB);
  __hip_bfloat16* xbc    = (__hip_bfloat16*)(ws + 80 * MB);
  __hip_bfloat16* dtY    = (__hip_bfloat16*)(ws + 112 * MB);
  float*          BiCi   = (float*)(ws + 144 * MB);
  __hip_bfloat16* W_ext  = (__hip_bfloat16*)(ws + 148 * MB);
  float*          hstart = (float*)(ws + 158 * MB);          // 16M
  float*          dtsum  = (float*)(ws + 174 * MB);          // 1M
  __hip_bfloat16* W_inT  = (__hip_bfloat16*)(ws + 177 * MB);
  float*          hfin   = (float*)(ws + 177 * MB);          // 16M after W_inT dead

  // 0+1. merged prep: LN + W_in^T + W_dt^T + wbc  (one launch)
  prep_kernel<<<TOKENS + 4096 + 4096 + 16, 256, 0, stream>>>(
      x, norm_scale, norm_bias, xn, W_in, W_inT, W_dt, W_ext, W_B, W_C);
  // 2. merged [xb|z] = xn @ W_in  (MODE 1 split)
  gemm_bf16<1><<<(4096 / BN) * (TOKENS / BM), 256, 0, stream>>>(
      xn, W_inT, xb, z, D_DIM, H_DIM, H_DIM, H_DIM, D_DIM, 4096 / BN,
      nullptr, nullptr);
  // (xn dead) convert W_out into S0
  dim3 tb(32, 8);
  transpose_bf16<<<dim3(1024 / 32, 2048 / 32), tb, 0, stream>>>(W_out, W_outT, 2048, 1024);
  // 3. depthwise conv + silu -> xbc bf16
  conv_silu_kernel<<<(TOKENS * D_DIM / 2) / 256, 256, 0, stream>>>(xb, conv_w, conv_b, xbc);
  // 4. fused: [dt | Bi | Ci] = xbc @ W_ext  (MODE 2: dt bf16+softplus, BiCi fp32)
  gemm_bf16<2><<<(NEXT / BN) * (TOKENS / BM), 256, 0, stream>>>(
      xbc, W_ext, dtY, BiCi, D_DIM, D_DIM, D_DIM, D_DIM, D_DIM, NEXT / BN,
      b_dt, nullptr);
  // 5. chunked scan: local -> combine -> rescan+gate (writes ybf, xb region dead)
  scan1_kernel<<<dim3(D_DIM / 256, CH, B_DIM), 256, 0, stream>>>(
      dtY, xbc, BiCi, A_log, hfin, dtsum);
  scan2_kernel<<<(B_DIM * D_DIM * N_STATE) / 256, 256, 0, stream>>>(
      hfin, dtsum, A_log, hstart);
  scan3_kernel<<<dim3(D_DIM / 256, CH, B_DIM), 256, 0, stream>>>(
      dtY, xbc, BiCi, A_log, hstart, z, D_param, ybf);
  // 6. out = x + y @ W_out   (MODE 0: fp32 + residual)
  gemm_bf16<0><<<(H_DIM / BN) * (TOKENS / BM), 256, 0, stream>>>(
      ybf, W_outT, out, nullptr, 1 << 30, D_DIM, D_DIM, D_DIM, H_DIM, H_DIM / BN,
      nullptr, x);
}